// Round 7
// baseline (208.099 us; speedup 1.0000x reference)
//
#include <hip/hip_runtime.h>

// SpatialAttention fp32: B=128, C=3, H=W=256, 8x8 patches, FEAT=192, ENC=16.
// R11: hide block-start global-load latency. Decomposition across rounds:
// R6 = 27us issue + 50 stall; R9 = 45 + 28; R10 = 31 + 40. The ~35-40us
// stall is invariant to occupancy (37-88%) and weight path -- VALU reshaping
// is exhausted. Untested suspect: every block starts with ~22 dependent
// global loads feeding the whole encoder; 3 barriers phalanx the 8 waves so
// the dead window never overlaps compute within a block.
// Fix: 2 patch-sets per block (grid 1024). xv[] is dead right after
// encode(A) -> set B's x-loads issue into the SAME registers immediately
// after, overlapping barA1+reduceA+decA+epiA (~60% of set time). Zero VGPR
// growth, 2x weight-preload amortization, half the launch/tail overhead.
// Also flip weight paths: encoder -> s_load (Wenc 12.3KB + biases fits sK$
// alone; decoder off scalar), decoder -> readlane wd[6] (R9-verified
// mapping). Drops we[16]: -16 regs, -16 straggler loads at block start.
// LDS-reuse safety: >=2 barriers separate every cross-set WAR on
// encl/hl2/sls. Tripwires: WRITE ~98.3MB, VGPR ~40-44; WRITE>110 = spill.

constexpr int NPATCH = 128 * 32 * 32;
constexpr float L2E  = 1.4426950408889634f;

__device__ __forceinline__ float rdlane(float v, int l) {
  return __uint_as_float(__builtin_amdgcn_readlane(__float_as_uint(v), l));
}

__global__ __launch_bounds__(512, 4) void spatial_attn(
    const float* __restrict__ x,      // [128][3][256][256]
    const float* __restrict__ Wenc,   // [16][192]
    const float* __restrict__ benc,   // [16]
    const float* __restrict__ Wdec,   // [192][16]
    const float* __restrict__ bdec,   // [192]
    float* __restrict__ y)            // [128][3][256][256]
{
  __shared__ float  encl[16 * 512];   // [e][tid] encoder partials (32 KB)
  __shared__ float2 hl2[8 * 64];      // [e-pair][patch-lane] relu'd h (4 KB)
  __shared__ float  sls[512];         // softmax partials (2 KB)

  const int tid  = threadIdx.x;
  const int lane = tid & 63;
  const int wv   = __builtin_amdgcn_readfirstlane(tid >> 6);  // uniform
  // Block owns 128 patches: setA = blk*128+lane, setB = +64 (same b: 128|1024)
  const int p0   = blockIdx.x * 128 + lane;
  const int b    = p0 >> 10;
  const int ii   = (p0 >> 5) & 31;
  const int jj   = p0 & 31;
  const size_t base0 = (size_t)b * 196608 + (size_t)ii * 2048 + (size_t)jj * 8;
  const size_t base1 = base0 + 4096;  // +64 patches = +2 ii rows

  // ---- Decoder weight slice -> VGPRs (one-time, coalesced 256B loads) ----
  float wd[6];                        // Wdec[wv*384 + k*64 + lane]
  #pragma unroll
  for (int k = 0; k < 6; ++k) wd[k] = Wdec[wv * 384 + k * 64 + lane];

  float2 xv2[12];                     // one set's 24 features (reused A->B)

  auto loadx = [&](size_t base) {
    #pragma unroll
    for (int t = 0; t < 3; ++t) {
      const int cr = 3 * wv + t;
      const float* src = x + base + (cr >> 3) * 65536 + (cr & 7) * 256;
      const float4 v0 = *(const float4*)(src);
      const float4 v1 = *(const float4*)(src + 4);
      xv2[t*4+0] = make_float2(v0.x, v0.y);
      xv2[t*4+1] = make_float2(v0.z, v0.w);
      xv2[t*4+2] = make_float2(v1.x, v1.y);
      xv2[t*4+3] = make_float2(v1.z, v1.w);
    }
  };

  // Encoder: weights via s_load (wave-uniform; scalar set = 12.3KB, sK$-hot)
  auto encode = [&]() {
    #pragma unroll
    for (int e = 0; e < 16; ++e) {
      const float* w = Wenc + e * 192 + wv * 24;   // uniform -> s_load
      float2 a2 = make_float2(0.0f, 0.0f);
      #pragma unroll
      for (int k = 0; k < 12; ++k) {
        a2.x = fmaf(w[2*k],   xv2[k].x, a2.x);
        a2.y = fmaf(w[2*k+1], xv2[k].y, a2.y);
      }
      encl[e * 512 + tid] = a2.x + a2.y;
    }
  };

  // Cross-wave reduce, de-dup: wave wv owns e-pair {2wv, 2wv+1}
  auto reduce = [&]() {
    const int e0 = 2 * wv;
    const float* c0 = encl + e0 * 512 + lane;
    const float* c1 = c0 + 512;
    float a0 = c0[0], a1 = c1[0];
    #pragma unroll
    for (int w8 = 1; w8 < 8; ++w8) { a0 += c0[w8 * 64]; a1 += c1[w8 * 64]; }
    hl2[wv * 64 + lane] = make_float2(fmaxf(a0 + benc[e0],     0.0f),
                                      fmaxf(a1 + benc[e0 + 1], 0.0f));
  };

  float o[24];

  // Decoder + softmax-partial for current h2; weights via readlane (VALU)
  auto decode = [&](const float2* h2, float& s) {
    s = 0.0f;
    #pragma unroll
    for (int q = 0; q < 24; ++q) {
      const int f = wv * 24 + q;
      float v = bdec[f];              // uniform scalar, tiny
      #pragma unroll
      for (int e = 0; e < 16; ++e) {
        const int idx = q * 16 + e;   // compile-time
        v = fmaf(rdlane(wd[idx >> 6], idx & 63), h2[e >> 1].x * (1 - (e & 1)) +
                 h2[e >> 1].y * (e & 1), v);
      }
      v = fmaxf(v, 0.0f);
      o[q] = v;
      s += __builtin_amdgcn_exp2f(v * L2E);
    }
  };

  auto epilogue = [&](size_t base, float inv) {
    #pragma unroll
    for (int t = 0; t < 3; ++t) {
      const int cr = 3 * wv + t;
      float* dst = y + base + (cr >> 3) * 65536 + (cr & 7) * 256;
      float r[8];
      #pragma unroll
      for (int c = 0; c < 8; ++c) {
        const float ov = o[t * 8 + c];
        r[c] = __builtin_amdgcn_exp2f(ov * L2E) * inv * ov;
      }
      *(float4*)(dst)     = (float4){r[0], r[1], r[2], r[3]};
      *(float4*)(dst + 4) = (float4){r[4], r[5], r[6], r[7]};
    }
  };

  // ================= set A =================
  loadx(base0);
  encode();
  loadx(base1);                       // PREFETCH set B into freed xv2 regs
  __syncthreads();                    // bar A1: encl ready
  reduce();
  __syncthreads();                    // bar A2: hl2 ready
  float2 h2[8];
  #pragma unroll
  for (int k = 0; k < 8; ++k) h2[k] = hl2[k * 64 + lane];
  float sA;
  decode(h2, sA);
  sls[tid] = sA;
  __syncthreads();                    // bar A3: sls ready
  float st = sls[lane];
  #pragma unroll
  for (int w8 = 1; w8 < 8; ++w8) st += sls[w8 * 64 + lane];
  epilogue(base0, __builtin_amdgcn_rcpf(st));

  // ================= set B =================
  encode();                           // xv2 already holds set B
  __syncthreads();                    // bar B1 (>=2 barriers since sls read)
  reduce();
  __syncthreads();                    // bar B2
  #pragma unroll
  for (int k = 0; k < 8; ++k) h2[k] = hl2[k * 64 + lane];
  float sB;
  decode(h2, sB);
  sls[tid] = sB;
  __syncthreads();                    // bar B3
  st = sls[lane];
  #pragma unroll
  for (int w8 = 1; w8 < 8; ++w8) st += sls[w8 * 64 + lane];
  epilogue(base1, __builtin_amdgcn_rcpf(st));
}

extern "C" void kernel_launch(void* const* d_in, const int* in_sizes, int n_in,
                              void* d_out, int out_size, void* d_ws, size_t ws_size,
                              hipStream_t stream) {
  const float* x    = (const float*)d_in[0];
  const float* Wenc = (const float*)d_in[1];
  const float* benc = (const float*)d_in[2];
  const float* Wdec = (const float*)d_in[3];
  const float* bdec = (const float*)d_in[4];
  float* y = (float*)d_out;
  dim3 grid(NPATCH / 128), block(512);
  hipLaunchKernelGGL(spatial_attn, grid, block, 0, stream, x, Wenc, benc, Wdec, bdec, y);
}